// Round 1
// 649.224 us; speedup vs baseline: 1.0425x; 1.0425x over previous
//
#include <hip/hip_runtime.h>
#include <math.h>

// N=50000, E=800000, IN=128, H=4, C=64, HC=256
#define HEADS 4
#define CH 64
#define HC 256

typedef short bf16x8 __attribute__((ext_vector_type(8)));
typedef float f32x4 __attribute__((ext_vector_type(4)));

__device__ __forceinline__ float leaky02(float x) { return x > 0.f ? x : 0.2f * x; }
__device__ __forceinline__ float bf2f(unsigned short u) {
  unsigned int v = ((unsigned int)u) << 16;
  return __builtin_bit_cast(float, v);
}
__device__ __forceinline__ unsigned short f2bf(float f) {
  unsigned int u = __builtin_bit_cast(unsigned int, f);
  unsigned int r = u + 0x7fffu + ((u >> 16) & 1u);
  return (unsigned short)(r >> 16);
}
__device__ __forceinline__ float decode_max(unsigned int key) {
  unsigned int mb = (key & 0x80000000u) ? (key & 0x7fffffffu) : ~key;
  return __builtin_bit_cast(float, mb);
}

// ---------------------------------------------------------------------------
// Convert input x fp32 [N*128] -> bf16
// ---------------------------------------------------------------------------
__global__ __launch_bounds__(256) void convert_x(const float* __restrict__ x,
                                                 unsigned short* __restrict__ xb,
                                                 int total4) {
  int i = blockIdx.x * 256 + threadIdx.x;
  if (i >= total4) return;
  float4 v = reinterpret_cast<const float4*>(x)[i];
  ushort4 o;
  o.x = f2bf(v.x); o.y = f2bf(v.y); o.z = f2bf(v.z); o.w = f2bf(v.w);
  reinterpret_cast<ushort4*>(xb)[i] = o;
}

// ---------------------------------------------------------------------------
// LDS-tiled transpose: Bt[512][K] bf16 = [W | SW]^T  (W/SW are [K][256] fp32)
// ---------------------------------------------------------------------------
__global__ __launch_bounds__(256) void transpose_w(const float* __restrict__ W,
                                                   const float* __restrict__ SW,
                                                   unsigned short* __restrict__ Bt, int K) {
  __shared__ unsigned short tile[64][72];
  int k0 = blockIdx.x * 64;
  int c0 = blockIdx.y * 64;
  const float* __restrict__ src = (c0 < 256) ? W : SW;
  int cc = (c0 < 256) ? c0 : c0 - 256;

  int t = threadIdx.x;
  int r = t >> 2, q4 = (t & 3) * 16;
#pragma unroll
  for (int q = 0; q < 4; q++) {
    float4 v = *reinterpret_cast<const float4*>(src + (size_t)(k0 + r) * 256 + cc + q4 + q * 4);
    tile[q4 + q * 4 + 0][r] = f2bf(v.x);
    tile[q4 + q * 4 + 1][r] = f2bf(v.y);
    tile[q4 + q * 4 + 2][r] = f2bf(v.z);
    tile[q4 + q * 4 + 3][r] = f2bf(v.w);
  }
  __syncthreads();
  int c = t >> 2, kq = (t & 3) * 16;
#pragma unroll
  for (int q = 0; q < 2; q++) {
    bf16x8 v = *reinterpret_cast<const bf16x8*>(&tile[c][kq + q * 8]);
    *reinterpret_cast<bf16x8*>(Bt + (size_t)(c0 + c) * K + k0 + kq + q * 8) = v;
  }
}

// ---------------------------------------------------------------------------
// bf16 MFMA GEMM: out[M][512] = x[M][K] @ [W|SW][K][512]
// Block 128x128, 4 waves, wave tile 64x64.
//   blockIdx.x 0..1 -> h (bf16) + FUSED s/d/smax epilogue; 2..3 -> skip (+Sb)
// Each wave's 64 cols == exactly one head (colBase+wc is a multiple of 64),
// so s[n,head]/d[n,head] are an in-register dot + cross-lrow shfl reduction,
// and the per-head global max is one encoded atomicMax per wave.
// ---------------------------------------------------------------------------
__global__ __launch_bounds__(256) void gemm_mfma(
    const unsigned short* __restrict__ xb, const unsigned short* __restrict__ Bt,
    const float* __restrict__ Sb, const float* __restrict__ a_src,
    const float* __restrict__ a_dst, unsigned short* __restrict__ h,
    unsigned short* __restrict__ skipb, float* __restrict__ s,
    float* __restrict__ d, unsigned int* __restrict__ smax_enc, int M, int K) {
  __shared__ unsigned short As[128 * 40];
  __shared__ unsigned short Bs[128 * 40];

  const int t = threadIdx.x;
  const int rowBase = blockIdx.y * 128;
  const int colBase = blockIdx.x * 128;  // 0..511
  const int w = t >> 6, lane = t & 63;
  const int wr = (w >> 1) * 64, wc = (w & 1) * 64;
  const int lrow = lane & 15, lq = lane >> 4;

  f32x4 acc[4][4];
#pragma unroll
  for (int i = 0; i < 4; i++)
#pragma unroll
    for (int j = 0; j < 4; j++) acc[i][j] = (f32x4){0.f, 0.f, 0.f, 0.f};

  for (int k0 = 0; k0 < K; k0 += 32) {
#pragma unroll
    for (int p = 0; p < 2; p++) {
      int flat = t + p * 256;
      int r = flat >> 2, seg = flat & 3;
      int gr = rowBase + r;
      if (gr >= M) gr = M - 1;
      bf16x8 av = *reinterpret_cast<const bf16x8*>(xb + (size_t)gr * K + k0 + seg * 8);
      *reinterpret_cast<bf16x8*>(&As[r * 40 + seg * 8]) = av;
      int gc = colBase + r;
      bf16x8 bv = *reinterpret_cast<const bf16x8*>(Bt + (size_t)gc * K + k0 + seg * 8);
      *reinterpret_cast<bf16x8*>(&Bs[r * 40 + seg * 8]) = bv;
    }
    __syncthreads();

    bf16x8 af[4], bfr[4];
#pragma unroll
    for (int i = 0; i < 4; i++) {
      af[i]  = *reinterpret_cast<const bf16x8*>(&As[(wr + i * 16 + lrow) * 40 + lq * 8]);
      bfr[i] = *reinterpret_cast<const bf16x8*>(&Bs[(wc + i * 16 + lrow) * 40 + lq * 8]);
    }
#pragma unroll
    for (int i = 0; i < 4; i++)
#pragma unroll
      for (int j = 0; j < 4; j++)
        acc[i][j] = __builtin_amdgcn_mfma_f32_16x16x32_bf16(af[i], bfr[j], acc[i][j], 0, 0, 0);
    __syncthreads();
  }

  // Epilogue: C/D layout col=lane&15, row=(lane>>4)*4+reg
  if (colBase < 256) {
#pragma unroll
    for (int i = 0; i < 4; i++) {
#pragma unroll
      for (int j = 0; j < 4; j++) {
        int gcol = colBase + wc + j * 16 + lrow;
#pragma unroll
        for (int r = 0; r < 4; r++) {
          int grow = rowBase + wr + i * 16 + lq * 4 + r;
          if (grow < M) h[(size_t)grow * 256 + gcol] = f2bf(acc[i][j][r]);
        }
      }
    }
    // --- fused s/d + global per-head max ---
    int head = (colBase + wc) >> 6;  // 0..3, one head per wave
    float as_w[4], ad_w[4];
#pragma unroll
    for (int j = 0; j < 4; j++) {
      as_w[j] = a_src[head * 64 + j * 16 + lrow];
      ad_w[j] = a_dst[head * 64 + j * 16 + lrow];
    }
    float mymax = -1e30f;
#pragma unroll
    for (int i = 0; i < 4; i++) {
#pragma unroll
      for (int r = 0; r < 4; r++) {
        float ps = acc[i][0][r] * as_w[0] + acc[i][1][r] * as_w[1] +
                   acc[i][2][r] * as_w[2] + acc[i][3][r] * as_w[3];
        float pd = acc[i][0][r] * ad_w[0] + acc[i][1][r] * ad_w[1] +
                   acc[i][2][r] * ad_w[2] + acc[i][3][r] * ad_w[3];
#pragma unroll
        for (int off = 1; off < 16; off <<= 1) {  // reduce across lrow (same lq)
          ps += __shfl_xor(ps, off, 64);
          pd += __shfl_xor(pd, off, 64);
        }
        int grow = rowBase + wr + i * 16 + lq * 4 + r;
        if (grow < M) {
          if (lrow == 0) { s[grow * 4 + head] = ps; d[grow * 4 + head] = pd; }
          mymax = fmaxf(mymax, ps);
        }
      }
    }
    mymax = fmaxf(mymax, __shfl_xor(mymax, 16, 64));
    mymax = fmaxf(mymax, __shfl_xor(mymax, 32, 64));
    if (lane == 0) {
      unsigned int mb = __builtin_bit_cast(unsigned int, mymax);
      unsigned int key = (mb & 0x80000000u) ? ~mb : (mb | 0x80000000u);
      atomicMax(&smax_enc[head], key);
    }
  } else {
#pragma unroll
    for (int i = 0; i < 4; i++) {
#pragma unroll
      for (int j = 0; j < 4; j++) {
        int c = colBase - 256 + wc + j * 16 + lrow;
        float sbv = Sb[c];
#pragma unroll
        for (int r = 0; r < 4; r++) {
          int grow = rowBase + wr + i * 16 + lq * 4 + r;
          if (grow < M) skipb[(size_t)grow * 256 + c] = f2bf(acc[i][j][r] + sbv);
        }
      }
    }
  }
}

// ---------------------------------------------------------------------------
// CSR build (padded to multiple-of-8 segments). Segment ORDER is irrelevant,
// so the exclusive scan is replaced by wave-aggregated atomicAdd on a cursor.
// ---------------------------------------------------------------------------
__global__ void hist_kernel(const int* __restrict__ ei, int* __restrict__ counts, int E) {
  int e = blockIdx.x * 256 + threadIdx.x;
  if (e < E) atomicAdd(&counts[ei[E + e]], 1);
}

__global__ __launch_bounds__(256) void offsets_kernel(
    const int* __restrict__ counts, int* __restrict__ offsets,
    int* __restrict__ cursor, int* __restrict__ total, int Nn) {
  int n = blockIdx.x * 256 + threadIdx.x;
  int lane = threadIdx.x & 63;
  int pc = (n < Nn) ? ((counts[n] + 7) & ~7) : 0;
  int incl = pc;
#pragma unroll
  for (int off = 1; off < 64; off <<= 1) {
    int tv = __shfl_up(incl, off, 64);
    if (lane >= off) incl += tv;
  }
  int wavesum = __shfl(incl, 63, 64);
  int base = 0;
  if (lane == 63) base = atomicAdd(total, wavesum);
  base = __shfl(base, 63, 64);
  if (n < Nn) {
    int pos = base + incl - pc;
    offsets[n] = pos;
    cursor[n] = pos;
  }
}

__global__ void scatter_kernel(const int* __restrict__ ei, int* __restrict__ cursor,
                               int* __restrict__ csr, int E) {
  int e = blockIdx.x * 256 + threadIdx.x;
  if (e < E) {
    int dn = ei[E + e];
    int pos = atomicAdd(&cursor[dn], 1);
    csr[pos] = ei[e];
  }
}

__global__ void pad_kernel(const int* __restrict__ counts, const int* __restrict__ offsets,
                           int* __restrict__ csr, int Nn) {
  int n = blockIdx.x * 256 + threadIdx.x;
  if (n >= Nn) return;
  int c = counts[n];
  int e0 = offsets[n] + c;
  int e1 = offsets[n] + ((c + 7) & ~7);
  for (int i = e0; i < e1; i++) csr[i] = 0;
}

// ---------------------------------------------------------------------------
// Aggregation v5 (fused edge softmax): one wave per node; 32 lanes per
// edge-row (8 cols/lane, b128 gathers); halves take interleaved 4-edge
// groups; combine via shfl_xor(32). exp(leaky(s+d)-m) computed inline:
// d/m are wave-constant, s gathered from the 800 KB L2-resident s-table.
// Padded slots masked against counts[n].
// ---------------------------------------------------------------------------
__global__ __launch_bounds__(256) void agg_kernel(
    const unsigned short* __restrict__ hb, const float* __restrict__ s,
    const float* __restrict__ d, const unsigned int* __restrict__ smax_enc,
    const int* __restrict__ offsets, const int* __restrict__ counts,
    const int* __restrict__ csr,
    const float* __restrict__ b, const unsigned short* __restrict__ skipb,
    float* __restrict__ xout_f, unsigned short* __restrict__ xout_b,
    int Nn, int write_f) {
  int n = blockIdx.x * 4 + (threadIdx.x >> 6);
  if (n >= Nn) return;
  int lane = threadIdx.x & 63;
  int sub = lane >> 5;
  int li = lane & 31;
  int head = li >> 3;
  int col = li * 8;

  int beg = offsets[n];
  int cnt = counts[n];
  int rend = beg + cnt;
  int pend = beg + ((cnt + 7) & ~7);

  float dv = d[n * 4 + head];
  float m = leaky02(decode_max(smax_enc[head]) + dv);

  float a[8] = {0.f, 0.f, 0.f, 0.f, 0.f, 0.f, 0.f, 0.f};
  float dsum = 0.f;

  for (int i = beg + sub * 4; i < pend; i += 8) {
    int4 sn = *reinterpret_cast<const int4*>(csr + i);
    float s0 = s[sn.x * 4 + head];
    float s1 = s[sn.y * 4 + head];
    float s2 = s[sn.z * 4 + head];
    float s3 = s[sn.w * 4 + head];
    float ev0 = (i + 0 < rend) ? __expf(leaky02(s0 + dv) - m) : 0.f;
    float ev1 = (i + 1 < rend) ? __expf(leaky02(s1 + dv) - m) : 0.f;
    float ev2 = (i + 2 < rend) ? __expf(leaky02(s2 + dv) - m) : 0.f;
    float ev3 = (i + 3 < rend) ? __expf(leaky02(s3 + dv) - m) : 0.f;
    bf16x8 u0 = *reinterpret_cast<const bf16x8*>(hb + (size_t)sn.x * HC + col);
    bf16x8 u1 = *reinterpret_cast<const bf16x8*>(hb + (size_t)sn.y * HC + col);
    bf16x8 u2 = *reinterpret_cast<const bf16x8*>(hb + (size_t)sn.z * HC + col);
    bf16x8 u3 = *reinterpret_cast<const bf16x8*>(hb + (size_t)sn.w * HC + col);
#pragma unroll
    for (int k = 0; k < 8; k++) {
      a[k] += ev0 * bf2f((unsigned short)u0[k]) + ev1 * bf2f((unsigned short)u1[k]) +
              ev2 * bf2f((unsigned short)u2[k]) + ev3 * bf2f((unsigned short)u3[k]);
    }
    dsum += ev0 + ev1 + ev2 + ev3;
  }

#pragma unroll
  for (int k = 0; k < 8; k++) a[k] += __shfl_xor(a[k], 32, 64);
  dsum += __shfl_xor(dsum, 32, 64);

  // self loop
  float sv = s[n * 4 + head];
  float es = __expf(leaky02(sv + dv) - m);
  bf16x8 hs = *reinterpret_cast<const bf16x8*>(hb + (size_t)n * HC + col);
#pragma unroll
  for (int k = 0; k < 8; k++) a[k] += es * bf2f((unsigned short)hs[k]);
  dsum += es;

  if (sub == 0) {
    float inv = 1.f / (dsum + 1e-16f);
    bf16x8 sk = *reinterpret_cast<const bf16x8*>(skipb + (size_t)n * HC + col);
    float4 b0 = *reinterpret_cast<const float4*>(b + col);
    float4 b1 = *reinterpret_cast<const float4*>(b + col + 4);
    float bv[8] = {b0.x, b0.y, b0.z, b0.w, b1.x, b1.y, b1.z, b1.w};
    float res[8];
#pragma unroll
    for (int k = 0; k < 8; k++) {
      float v = a[k] * inv + bv[k] + bf2f((unsigned short)sk[k]);
      res[k] = v > 0.f ? v : expm1f(v);
    }
    if (write_f) {
      float4 r0 = make_float4(res[0], res[1], res[2], res[3]);
      float4 r1 = make_float4(res[4], res[5], res[6], res[7]);
      *reinterpret_cast<float4*>(xout_f + (size_t)n * HC + col) = r0;
      *reinterpret_cast<float4*>(xout_f + (size_t)n * HC + col + 4) = r1;
    } else {
      bf16x8 o;
#pragma unroll
      for (int k = 0; k < 8; k++) o[k] = (short)f2bf(res[k]);
      *reinterpret_cast<bf16x8*>(xout_b + (size_t)n * HC + col) = o;
    }
  }
}

// ---------------------------------------------------------------------------
extern "C" void kernel_launch(void* const* d_in, const int* in_sizes, int n_in,
                              void* d_out, int out_size, void* d_ws, size_t ws_size,
                              hipStream_t stream) {
  const float* x = (const float*)d_in[0];
  const int* ei = (const int*)d_in[1];
  const int Nn = in_sizes[0] / 128;  // 50000
  const int E = in_sizes[1] / 2;     // 800000
  const int EPS = E + 7 * Nn;        // max padded CSR size (pad-8)

  const float* W[3]; const float* asrc[3]; const float* adst[3];
  const float* bb[3]; const float* SW[3]; const float* Sb[3];
  for (int l = 0; l < 3; l++) {
    W[l]    = (const float*)d_in[2 + 6 * l + 0];
    asrc[l] = (const float*)d_in[2 + 6 * l + 1];
    adst[l] = (const float*)d_in[2 + 6 * l + 2];
    bb[l]   = (const float*)d_in[2 + 6 * l + 3];
    SW[l]   = (const float*)d_in[2 + 6 * l + 4];
    Sb[l]   = (const float*)d_in[2 + 6 * l + 5];
  }

  // Workspace layout (16B aligned chunks). counts, total, smax_enc adjacent so
  // a single memset clears all three (smax uses 4 slots per layer, 12 total).
  char* p = (char*)d_ws;
  unsigned short* hb    = (unsigned short*)p; p += (size_t)Nn * HC * 2;
  unsigned short* xb    = (unsigned short*)p; p += (size_t)Nn * HC * 2;
  unsigned short* x1b   = (unsigned short*)p; p += (size_t)Nn * 128 * 2;
  unsigned short* Bt    = (unsigned short*)p; p += (size_t)512 * 256 * 2;
  unsigned short* skipb = (unsigned short*)p; p += (size_t)Nn * HC * 2;
  float* sbuf  = (float*)p; p += (size_t)Nn * HEADS * 4;
  float* dbuf  = (float*)p; p += (size_t)Nn * HEADS * 4;
  int* counts  = (int*)p; p += (size_t)Nn * 4;
  int* total   = (int*)p; p += 16;
  unsigned int* smax_enc = (unsigned int*)p; p += 64;
  int* offsets = (int*)p; p += ((size_t)Nn * 4 + 15) & ~(size_t)15;
  int* cursor  = (int*)p; p += ((size_t)Nn * 4 + 15) & ~(size_t)15;
  int* csr     = (int*)p; p += (size_t)EPS * 4;

  // --- CSR build (once; dst is layer-invariant). One memset covers
  // counts+total+smax. Segment order is atomic-assigned (irrelevant to result).
  hipMemsetAsync(counts, 0, (size_t)Nn * 4 + 16 + 64, stream);
  hist_kernel<<<(E + 255) / 256, 256, 0, stream>>>(ei, counts, E);
  offsets_kernel<<<(Nn + 255) / 256, 256, 0, stream>>>(counts, offsets, cursor, total, Nn);
  scatter_kernel<<<(E + 255) / 256, 256, 0, stream>>>(ei, cursor, csr, E);
  pad_kernel<<<(Nn + 255) / 256, 256, 0, stream>>>(counts, offsets, csr, Nn);

  // --- Input conversion ---
  int t4 = Nn * 128 / 4;
  convert_x<<<(t4 + 255) / 256, 256, 0, stream>>>(x, x1b, t4);

  // --- Layers ---
  dim3 ggrid(4, (Nn + 127) / 128);
  int nblk4 = (Nn + 3) / 4;
  for (int l = 0; l < 3; l++) {
    int K = (l == 0) ? 128 : 256;
    const unsigned short* xin = (l == 0) ? x1b : xb;
    unsigned int* sme = smax_enc + 4 * l;
    transpose_w<<<dim3(K / 64, 8), 256, 0, stream>>>(W[l], SW[l], Bt, K);
    gemm_mfma<<<ggrid, 256, 0, stream>>>(xin, Bt, Sb[l], asrc[l], adst[l],
                                         hb, skipb, sbuf, dbuf, sme, Nn, K);
    agg_kernel<<<nblk4, 256, 0, stream>>>(hb, sbuf, dbuf, sme, offsets, counts, csr,
                                          bb[l], skipb, (float*)d_out, xb,
                                          Nn, (l == 2) ? 1 : 0);
  }
}

// Round 2
// 643.687 us; speedup vs baseline: 1.0514x; 1.0086x over previous
//
#include <hip/hip_runtime.h>
#include <math.h>

// N=50000, E=800000, IN=128, H=4, C=64, HC=256
#define HEADS 4
#define CH 64
#define HC 256

typedef short bf16x8 __attribute__((ext_vector_type(8)));
typedef float f32x4 __attribute__((ext_vector_type(4)));

__device__ __forceinline__ float leaky02(float x) { return x > 0.f ? x : 0.2f * x; }
__device__ __forceinline__ float bf2f(unsigned short u) {
  unsigned int v = ((unsigned int)u) << 16;
  return __builtin_bit_cast(float, v);
}
__device__ __forceinline__ unsigned short f2bf(float f) {
  unsigned int u = __builtin_bit_cast(unsigned int, f);
  unsigned int r = u + 0x7fffu + ((u >> 16) & 1u);
  return (unsigned short)(r >> 16);
}
__device__ __forceinline__ float decode_max(unsigned int key) {
  unsigned int mb = (key & 0x80000000u) ? (key & 0x7fffffffu) : ~key;
  return __builtin_bit_cast(float, mb);
}

// Async global->LDS, 16B per lane. LDS dest is lane-linear (base + lane*16).
__device__ __forceinline__ void gload_lds16(const unsigned short* g, unsigned short* l) {
  __builtin_amdgcn_global_load_lds(
      (const __attribute__((address_space(1))) unsigned int*)g,
      (__attribute__((address_space(3))) unsigned int*)l, 16, 0, 0);
}

// ---------------------------------------------------------------------------
// Convert input x fp32 [N*128] -> bf16
// ---------------------------------------------------------------------------
__global__ __launch_bounds__(256) void convert_x(const float* __restrict__ x,
                                                 unsigned short* __restrict__ xb,
                                                 int total4) {
  int i = blockIdx.x * 256 + threadIdx.x;
  if (i >= total4) return;
  float4 v = reinterpret_cast<const float4*>(x)[i];
  ushort4 o;
  o.x = f2bf(v.x); o.y = f2bf(v.y); o.z = f2bf(v.z); o.w = f2bf(v.w);
  reinterpret_cast<ushort4*>(xb)[i] = o;
}

// ---------------------------------------------------------------------------
// LDS-tiled transpose: Bt[512][K] bf16 = [W | SW]^T  (W/SW are [K][256] fp32)
// ---------------------------------------------------------------------------
__global__ __launch_bounds__(256) void transpose_w(const float* __restrict__ W,
                                                   const float* __restrict__ SW,
                                                   unsigned short* __restrict__ Bt, int K) {
  __shared__ unsigned short tile[64][72];
  int k0 = blockIdx.x * 64;
  int c0 = blockIdx.y * 64;
  const float* __restrict__ src = (c0 < 256) ? W : SW;
  int cc = (c0 < 256) ? c0 : c0 - 256;

  int t = threadIdx.x;
  int r = t >> 2, q4 = (t & 3) * 16;
#pragma unroll
  for (int q = 0; q < 4; q++) {
    float4 v = *reinterpret_cast<const float4*>(src + (size_t)(k0 + r) * 256 + cc + q4 + q * 4);
    tile[q4 + q * 4 + 0][r] = f2bf(v.x);
    tile[q4 + q * 4 + 1][r] = f2bf(v.y);
    tile[q4 + q * 4 + 2][r] = f2bf(v.z);
    tile[q4 + q * 4 + 3][r] = f2bf(v.w);
  }
  __syncthreads();
  int c = t >> 2, kq = (t & 3) * 16;
#pragma unroll
  for (int q = 0; q < 2; q++) {
    bf16x8 v = *reinterpret_cast<const bf16x8*>(&tile[c][kq + q * 8]);
    *reinterpret_cast<bf16x8*>(Bt + (size_t)(c0 + c) * K + k0 + kq + q * 8) = v;
  }
}

// ---------------------------------------------------------------------------
// bf16 MFMA GEMM (m97 structure): out[M][512] = x[M][K] @ [W|SW][K][512]
// Block 128x128, 4 waves, wave tile 64x64. Double-buffered LDS, async
// global_load_lds width-16 staging, ONE barrier per K-step.
// LDS layout: linear chunks of 16B; chunk c (0..511): row=c>>2, kseg=c&3.
// Fragment read (row*64B + lq*16B) is bank-conflict-free (even 8-group spread).
//   blockIdx.x 0..1 -> h (bf16) + FUSED s/d/smax epilogue; 2..3 -> skip (+Sb)
// ---------------------------------------------------------------------------
__global__ __launch_bounds__(256) void gemm_mfma(
    const unsigned short* __restrict__ xb, const unsigned short* __restrict__ Bt,
    const float* __restrict__ Sb, const float* __restrict__ a_src,
    const float* __restrict__ a_dst, unsigned short* __restrict__ h,
    unsigned short* __restrict__ skipb, float* __restrict__ s,
    float* __restrict__ d, unsigned int* __restrict__ smax_enc, int M, int K) {
  __shared__ unsigned short As[2][128 * 32];
  __shared__ unsigned short Bs[2][128 * 32];

  const int t = threadIdx.x;
  const int rowBase = blockIdx.y * 128;
  const int colBase = blockIdx.x * 128;  // 0..511
  const int w = t >> 6, lane = t & 63;
  const int wr = (w >> 1) * 64, wc = (w & 1) * 64;
  const int lrow = lane & 15, lq = lane >> 4;

  // Per-thread staging sources: chunks c0=t and c1=t+256.
  const int r0 = t >> 2, seg = t & 3;
  int gr0 = rowBase + r0;       if (gr0 >= M) gr0 = M - 1;
  int gr1 = rowBase + 64 + r0;  if (gr1 >= M) gr1 = M - 1;
  const unsigned short* gA0 = xb + (size_t)gr0 * K + seg * 8;
  const unsigned short* gA1 = xb + (size_t)gr1 * K + seg * 8;
  const unsigned short* gB0 = Bt + (size_t)(colBase + r0) * K + seg * 8;
  const unsigned short* gB1 = Bt + (size_t)(colBase + 64 + r0) * K + seg * 8;
  unsigned short* lA0;
  unsigned short* lA1;
  unsigned short* lB0;
  unsigned short* lB1;

  f32x4 acc[4][4];
#pragma unroll
  for (int i = 0; i < 4; i++)
#pragma unroll
    for (int j = 0; j < 4; j++) acc[i][j] = (f32x4){0.f, 0.f, 0.f, 0.f};

  const int nt = K >> 5;

  // prologue: stage step 0 into buffer 0
  lA0 = &As[0][t * 8]; lA1 = &As[0][(t + 256) * 8];
  lB0 = &Bs[0][t * 8]; lB1 = &Bs[0][(t + 256) * 8];
  gload_lds16(gA0, lA0); gload_lds16(gA1, lA1);
  gload_lds16(gB0, lB0); gload_lds16(gB1, lB1);
  __syncthreads();  // compiler drains vmcnt(0) before s_barrier

  for (int st = 0; st < nt; ++st) {
    const int cur = st & 1;
    if (st + 1 < nt) {
      const int nxt = cur ^ 1;
      const int ko = (st + 1) * 32;
      gload_lds16(gA0 + ko, &As[nxt][t * 8]);
      gload_lds16(gA1 + ko, &As[nxt][(t + 256) * 8]);
      gload_lds16(gB0 + ko, &Bs[nxt][t * 8]);
      gload_lds16(gB1 + ko, &Bs[nxt][(t + 256) * 8]);
    }
    bf16x8 af[4], bfr[4];
#pragma unroll
    for (int i = 0; i < 4; i++) {
      af[i]  = *reinterpret_cast<const bf16x8*>(&As[cur][(wr + i * 16 + lrow) * 32 + lq * 8]);
      bfr[i] = *reinterpret_cast<const bf16x8*>(&Bs[cur][(wc + i * 16 + lrow) * 32 + lq * 8]);
    }
#pragma unroll
    for (int i = 0; i < 4; i++)
#pragma unroll
      for (int j = 0; j < 4; j++)
        acc[i][j] = __builtin_amdgcn_mfma_f32_16x16x32_bf16(af[i], bfr[j], acc[i][j], 0, 0, 0);
    if (st + 1 < nt) __syncthreads();  // drain next-step loads + release buffers
  }

  // Epilogue: C/D layout col=lane&15, row=(lane>>4)*4+reg
  if (colBase < 256) {
#pragma unroll
    for (int i = 0; i < 4; i++) {
#pragma unroll
      for (int j = 0; j < 4; j++) {
        int gcol = colBase + wc + j * 16 + lrow;
#pragma unroll
        for (int r = 0; r < 4; r++) {
          int grow = rowBase + wr + i * 16 + lq * 4 + r;
          if (grow < M) h[(size_t)grow * 256 + gcol] = f2bf(acc[i][j][r]);
        }
      }
    }
    // --- fused s/d + global per-head max ---
    int head = (colBase + wc) >> 6;  // 0..3, one head per wave
    float as_w[4], ad_w[4];
#pragma unroll
    for (int j = 0; j < 4; j++) {
      as_w[j] = a_src[head * 64 + j * 16 + lrow];
      ad_w[j] = a_dst[head * 64 + j * 16 + lrow];
    }
    float mymax = -1e30f;
#pragma unroll
    for (int i = 0; i < 4; i++) {
#pragma unroll
      for (int r = 0; r < 4; r++) {
        float ps = acc[i][0][r] * as_w[0] + acc[i][1][r] * as_w[1] +
                   acc[i][2][r] * as_w[2] + acc[i][3][r] * as_w[3];
        float pd = acc[i][0][r] * ad_w[0] + acc[i][1][r] * ad_w[1] +
                   acc[i][2][r] * ad_w[2] + acc[i][3][r] * ad_w[3];
#pragma unroll
        for (int off = 1; off < 16; off <<= 1) {  // reduce across lrow (same lq)
          ps += __shfl_xor(ps, off, 64);
          pd += __shfl_xor(pd, off, 64);
        }
        int grow = rowBase + wr + i * 16 + lq * 4 + r;
        if (grow < M) {
          if (lrow == 0) { s[grow * 4 + head] = ps; d[grow * 4 + head] = pd; }
          mymax = fmaxf(mymax, ps);
        }
      }
    }
    mymax = fmaxf(mymax, __shfl_xor(mymax, 16, 64));
    mymax = fmaxf(mymax, __shfl_xor(mymax, 32, 64));
    if (lane == 0) {
      unsigned int mb = __builtin_bit_cast(unsigned int, mymax);
      unsigned int key = (mb & 0x80000000u) ? ~mb : (mb | 0x80000000u);
      atomicMax(&smax_enc[head], key);
    }
  } else {
#pragma unroll
    for (int i = 0; i < 4; i++) {
#pragma unroll
      for (int j = 0; j < 4; j++) {
        int c = colBase - 256 + wc + j * 16 + lrow;
        float sbv = Sb[c];
#pragma unroll
        for (int r = 0; r < 4; r++) {
          int grow = rowBase + wr + i * 16 + lq * 4 + r;
          if (grow < M) skipb[(size_t)grow * 256 + c] = f2bf(acc[i][j][r] + sbv);
        }
      }
    }
  }
}

// ---------------------------------------------------------------------------
// CSR build (padded to multiple-of-8 segments). Segment ORDER is irrelevant,
// so the exclusive scan is replaced by wave-aggregated atomicAdd on a cursor.
// ---------------------------------------------------------------------------
__global__ void hist_kernel(const int* __restrict__ ei, int* __restrict__ counts, int E) {
  int e = blockIdx.x * 256 + threadIdx.x;
  if (e < E) atomicAdd(&counts[ei[E + e]], 1);
}

__global__ __launch_bounds__(256) void offsets_kernel(
    const int* __restrict__ counts, int* __restrict__ offsets,
    int* __restrict__ cursor, int* __restrict__ total, int Nn) {
  int n = blockIdx.x * 256 + threadIdx.x;
  int lane = threadIdx.x & 63;
  int pc = (n < Nn) ? ((counts[n] + 7) & ~7) : 0;
  int incl = pc;
#pragma unroll
  for (int off = 1; off < 64; off <<= 1) {
    int tv = __shfl_up(incl, off, 64);
    if (lane >= off) incl += tv;
  }
  int wavesum = __shfl(incl, 63, 64);
  int base = 0;
  if (lane == 63) base = atomicAdd(total, wavesum);
  base = __shfl(base, 63, 64);
  if (n < Nn) {
    int pos = base + incl - pc;
    offsets[n] = pos;
    cursor[n] = pos;
  }
}

__global__ void scatter_kernel(const int* __restrict__ ei, int* __restrict__ cursor,
                               int* __restrict__ csr, int E) {
  int e = blockIdx.x * 256 + threadIdx.x;
  if (e < E) {
    int dn = ei[E + e];
    int pos = atomicAdd(&cursor[dn], 1);
    csr[pos] = ei[e];
  }
}

__global__ void pad_kernel(const int* __restrict__ counts, const int* __restrict__ offsets,
                           int* __restrict__ csr, int Nn) {
  int n = blockIdx.x * 256 + threadIdx.x;
  if (n >= Nn) return;
  int c = counts[n];
  int e0 = offsets[n] + c;
  int e1 = offsets[n] + ((c + 7) & ~7);
  for (int i = e0; i < e1; i++) csr[i] = 0;
}

// ---------------------------------------------------------------------------
// Aggregation (fused edge softmax): one wave per node; 32 lanes per edge-row
// (8 cols/lane, b128 gathers); halves take interleaved 4-edge groups;
// combine via shfl_xor(32). exp(leaky(s+d)-m) computed inline.
// ---------------------------------------------------------------------------
__global__ __launch_bounds__(256) void agg_kernel(
    const unsigned short* __restrict__ hb, const float* __restrict__ s,
    const float* __restrict__ d, const unsigned int* __restrict__ smax_enc,
    const int* __restrict__ offsets, const int* __restrict__ counts,
    const int* __restrict__ csr,
    const float* __restrict__ b, const unsigned short* __restrict__ skipb,
    float* __restrict__ xout_f, unsigned short* __restrict__ xout_b,
    int Nn, int write_f) {
  int n = blockIdx.x * 4 + (threadIdx.x >> 6);
  if (n >= Nn) return;
  int lane = threadIdx.x & 63;
  int sub = lane >> 5;
  int li = lane & 31;
  int head = li >> 3;
  int col = li * 8;

  int beg = offsets[n];
  int cnt = counts[n];
  int rend = beg + cnt;
  int pend = beg + ((cnt + 7) & ~7);

  float dv = d[n * 4 + head];
  float m = leaky02(decode_max(smax_enc[head]) + dv);

  float a[8] = {0.f, 0.f, 0.f, 0.f, 0.f, 0.f, 0.f, 0.f};
  float dsum = 0.f;

  for (int i = beg + sub * 4; i < pend; i += 8) {
    int4 sn = *reinterpret_cast<const int4*>(csr + i);
    float s0 = s[sn.x * 4 + head];
    float s1 = s[sn.y * 4 + head];
    float s2 = s[sn.z * 4 + head];
    float s3 = s[sn.w * 4 + head];
    float ev0 = (i + 0 < rend) ? __expf(leaky02(s0 + dv) - m) : 0.f;
    float ev1 = (i + 1 < rend) ? __expf(leaky02(s1 + dv) - m) : 0.f;
    float ev2 = (i + 2 < rend) ? __expf(leaky02(s2 + dv) - m) : 0.f;
    float ev3 = (i + 3 < rend) ? __expf(leaky02(s3 + dv) - m) : 0.f;
    bf16x8 u0 = *reinterpret_cast<const bf16x8*>(hb + (size_t)sn.x * HC + col);
    bf16x8 u1 = *reinterpret_cast<const bf16x8*>(hb + (size_t)sn.y * HC + col);
    bf16x8 u2 = *reinterpret_cast<const bf16x8*>(hb + (size_t)sn.z * HC + col);
    bf16x8 u3 = *reinterpret_cast<const bf16x8*>(hb + (size_t)sn.w * HC + col);
#pragma unroll
    for (int k = 0; k < 8; k++) {
      a[k] += ev0 * bf2f((unsigned short)u0[k]) + ev1 * bf2f((unsigned short)u1[k]) +
              ev2 * bf2f((unsigned short)u2[k]) + ev3 * bf2f((unsigned short)u3[k]);
    }
    dsum += ev0 + ev1 + ev2 + ev3;
  }

#pragma unroll
  for (int k = 0; k < 8; k++) a[k] += __shfl_xor(a[k], 32, 64);
  dsum += __shfl_xor(dsum, 32, 64);

  // self loop
  float sv = s[n * 4 + head];
  float es = __expf(leaky02(sv + dv) - m);
  bf16x8 hs = *reinterpret_cast<const bf16x8*>(hb + (size_t)n * HC + col);
#pragma unroll
  for (int k = 0; k < 8; k++) a[k] += es * bf2f((unsigned short)hs[k]);
  dsum += es;

  if (sub == 0) {
    float inv = 1.f / (dsum + 1e-16f);
    bf16x8 sk = *reinterpret_cast<const bf16x8*>(skipb + (size_t)n * HC + col);
    float4 b0 = *reinterpret_cast<const float4*>(b + col);
    float4 b1 = *reinterpret_cast<const float4*>(b + col + 4);
    float bv[8] = {b0.x, b0.y, b0.z, b0.w, b1.x, b1.y, b1.z, b1.w};
    float res[8];
#pragma unroll
    for (int k = 0; k < 8; k++) {
      float v = a[k] * inv + bv[k] + bf2f((unsigned short)sk[k]);
      res[k] = v > 0.f ? v : expm1f(v);
    }
    if (write_f) {
      float4 r0 = make_float4(res[0], res[1], res[2], res[3]);
      float4 r1 = make_float4(res[4], res[5], res[6], res[7]);
      *reinterpret_cast<float4*>(xout_f + (size_t)n * HC + col) = r0;
      *reinterpret_cast<float4*>(xout_f + (size_t)n * HC + col + 4) = r1;
    } else {
      bf16x8 o;
#pragma unroll
      for (int k = 0; k < 8; k++) o[k] = (short)f2bf(res[k]);
      *reinterpret_cast<bf16x8*>(xout_b + (size_t)n * HC + col) = o;
    }
  }
}

// ---------------------------------------------------------------------------
extern "C" void kernel_launch(void* const* d_in, const int* in_sizes, int n_in,
                              void* d_out, int out_size, void* d_ws, size_t ws_size,
                              hipStream_t stream) {
  const float* x = (const float*)d_in[0];
  const int* ei = (const int*)d_in[1];
  const int Nn = in_sizes[0] / 128;  // 50000
  const int E = in_sizes[1] / 2;     // 800000
  const int EPS = E + 7 * Nn;        // max padded CSR size (pad-8)

  const float* W[3]; const float* asrc[3]; const float* adst[3];
  const float* bb[3]; const float* SW[3]; const float* Sb[3];
  for (int l = 0; l < 3; l++) {
    W[l]    = (const float*)d_in[2 + 6 * l + 0];
    asrc[l] = (const float*)d_in[2 + 6 * l + 1];
    adst[l] = (const float*)d_in[2 + 6 * l + 2];
    bb[l]   = (const float*)d_in[2 + 6 * l + 3];
    SW[l]   = (const float*)d_in[2 + 6 * l + 4];
    Sb[l]   = (const float*)d_in[2 + 6 * l + 5];
  }

  // Workspace layout (16B aligned chunks). counts, total, smax_enc adjacent so
  // a single memset clears all three (smax uses 4 slots per layer, 12 total).
  char* p = (char*)d_ws;
  unsigned short* hb    = (unsigned short*)p; p += (size_t)Nn * HC * 2;
  unsigned short* xb    = (unsigned short*)p; p += (size_t)Nn * HC * 2;
  unsigned short* x1b   = (unsigned short*)p; p += (size_t)Nn * 128 * 2;
  unsigned short* Bt    = (unsigned short*)p; p += (size_t)512 * 256 * 2;
  unsigned short* skipb = (unsigned short*)p; p += (size_t)Nn * HC * 2;
  float* sbuf  = (float*)p; p += (size_t)Nn * HEADS * 4;
  float* dbuf  = (float*)p; p += (size_t)Nn * HEADS * 4;
  int* counts  = (int*)p; p += (size_t)Nn * 4;
  int* total   = (int*)p; p += 16;
  unsigned int* smax_enc = (unsigned int*)p; p += 64;
  int* offsets = (int*)p; p += ((size_t)Nn * 4 + 15) & ~(size_t)15;
  int* cursor  = (int*)p; p += ((size_t)Nn * 4 + 15) & ~(size_t)15;
  int* csr     = (int*)p; p += (size_t)EPS * 4;

  // --- CSR build (once; dst is layer-invariant). One memset covers
  // counts+total+smax. Segment order is atomic-assigned (irrelevant to result).
  hipMemsetAsync(counts, 0, (size_t)Nn * 4 + 16 + 64, stream);
  hist_kernel<<<(E + 255) / 256, 256, 0, stream>>>(ei, counts, E);
  offsets_kernel<<<(Nn + 255) / 256, 256, 0, stream>>>(counts, offsets, cursor, total, Nn);
  scatter_kernel<<<(E + 255) / 256, 256, 0, stream>>>(ei, cursor, csr, E);
  pad_kernel<<<(Nn + 255) / 256, 256, 0, stream>>>(counts, offsets, csr, Nn);

  // --- Input conversion ---
  int t4 = Nn * 128 / 4;
  convert_x<<<(t4 + 255) / 256, 256, 0, stream>>>(x, x1b, t4);

  // --- Layers ---
  dim3 ggrid(4, (Nn + 127) / 128);
  int nblk4 = (Nn + 3) / 4;
  for (int l = 0; l < 3; l++) {
    int K = (l == 0) ? 128 : 256;
    const unsigned short* xin = (l == 0) ? x1b : xb;
    unsigned int* sme = smax_enc + 4 * l;
    transpose_w<<<dim3(K / 64, 8), 256, 0, stream>>>(W[l], SW[l], Bt, K);
    gemm_mfma<<<ggrid, 256, 0, stream>>>(xin, Bt, Sb[l], asrc[l], adst[l],
                                         hb, skipb, sbuf, dbuf, sme, Nn, K);
    agg_kernel<<<nblk4, 256, 0, stream>>>(hb, sbuf, dbuf, sme, offsets, counts, csr,
                                          bb[l], skipb, (float*)d_out, xb,
                                          Nn, (l == 2) ? 1 : 0);
  }
}

// Round 3
// 640.772 us; speedup vs baseline: 1.0562x; 1.0045x over previous
//
#include <hip/hip_runtime.h>
#include <math.h>

// N=50000, E=800000, IN=128, H=4, C=64, HC=256
#define HEADS 4
#define CH 64
#define HC 256

typedef short bf16x8 __attribute__((ext_vector_type(8)));
typedef float f32x4 __attribute__((ext_vector_type(4)));

__device__ __forceinline__ float leaky02(float x) { return x > 0.f ? x : 0.2f * x; }
__device__ __forceinline__ float bf2f(unsigned short u) {
  unsigned int v = ((unsigned int)u) << 16;
  return __builtin_bit_cast(float, v);
}
__device__ __forceinline__ unsigned short f2bf(float f) {
  unsigned int u = __builtin_bit_cast(unsigned int, f);
  unsigned int r = u + 0x7fffu + ((u >> 16) & 1u);
  return (unsigned short)(r >> 16);
}
__device__ __forceinline__ float decode_max(unsigned int key) {
  unsigned int mb = (key & 0x80000000u) ? (key & 0x7fffffffu) : ~key;
  return __builtin_bit_cast(float, mb);
}

// Async global->LDS, 16B per lane. LDS dest is lane-linear (base + lane*16).
__device__ __forceinline__ void gload_lds16(const unsigned short* g, unsigned short* l) {
  __builtin_amdgcn_global_load_lds(
      (const __attribute__((address_space(1))) unsigned int*)g,
      (__attribute__((address_space(3))) unsigned int*)l, 16, 0, 0);
}

// Opaque LDS b128 read (keeps compiler waitcnt logic out of the pipelined loop).
__device__ __forceinline__ bf16x8 lds_read_b128(unsigned int byte_off) {
  bf16x8 r;
  asm volatile("ds_read_b128 %0, %1" : "=&v"(r) : "v"(byte_off));
  return r;
}

// ---------------------------------------------------------------------------
// Convert input x fp32 [N*128] -> bf16
// ---------------------------------------------------------------------------
__global__ __launch_bounds__(256) void convert_x(const float* __restrict__ x,
                                                 unsigned short* __restrict__ xb,
                                                 int total4) {
  int i = blockIdx.x * 256 + threadIdx.x;
  if (i >= total4) return;
  float4 v = reinterpret_cast<const float4*>(x)[i];
  ushort4 o;
  o.x = f2bf(v.x); o.y = f2bf(v.y); o.z = f2bf(v.z); o.w = f2bf(v.w);
  reinterpret_cast<ushort4*>(xb)[i] = o;
}

// ---------------------------------------------------------------------------
// LDS-tiled transpose: Bt[512][K] bf16 = [W | SW]^T  (W/SW are [K][256] fp32)
// ---------------------------------------------------------------------------
__global__ __launch_bounds__(256) void transpose_w(const float* __restrict__ W,
                                                   const float* __restrict__ SW,
                                                   unsigned short* __restrict__ Bt, int K) {
  __shared__ unsigned short tile[64][72];
  int k0 = blockIdx.x * 64;
  int c0 = blockIdx.y * 64;
  const float* __restrict__ src = (c0 < 256) ? W : SW;
  int cc = (c0 < 256) ? c0 : c0 - 256;

  int t = threadIdx.x;
  int r = t >> 2, q4 = (t & 3) * 16;
#pragma unroll
  for (int q = 0; q < 4; q++) {
    float4 v = *reinterpret_cast<const float4*>(src + (size_t)(k0 + r) * 256 + cc + q4 + q * 4);
    tile[q4 + q * 4 + 0][r] = f2bf(v.x);
    tile[q4 + q * 4 + 1][r] = f2bf(v.y);
    tile[q4 + q * 4 + 2][r] = f2bf(v.z);
    tile[q4 + q * 4 + 3][r] = f2bf(v.w);
  }
  __syncthreads();
  int c = t >> 2, kq = (t & 3) * 16;
#pragma unroll
  for (int q = 0; q < 2; q++) {
    bf16x8 v = *reinterpret_cast<const bf16x8*>(&tile[c][kq + q * 8]);
    *reinterpret_cast<bf16x8*>(Bt + (size_t)(c0 + c) * K + k0 + kq + q * 8) = v;
  }
}

// ---------------------------------------------------------------------------
// bf16 MFMA GEMM, 4-deep counted-vmcnt pipeline (T3/T4):
// out[M][512] = x[M][K] @ [W|SW][K][512]
// Block 128x128, 4 waves, wave tile 64x64. 4 LDS buffer sets (64KB).
// Prologue issues steps 0..2; iter st: s_waitcnt vmcnt(8) (2 steps stay in
// flight -> never drain to 0), raw s_barrier, issue st+3, asm ds_read frags,
// lgkmcnt(0)+sched_barrier, 16 MFMA. Buffer (st+3)&3 == (st-1)&3 is free:
// all waves retired their st-1 ds_reads before passing this barrier.
//   blockIdx.x 0..1 -> h (bf16) + FUSED s/d/smax epilogue; 2..3 -> skip (+Sb)
// ---------------------------------------------------------------------------
__global__ __launch_bounds__(256) void gemm_mfma(
    const unsigned short* __restrict__ xb, const unsigned short* __restrict__ Bt,
    const float* __restrict__ Sb, const float* __restrict__ a_src,
    const float* __restrict__ a_dst, unsigned short* __restrict__ h,
    unsigned short* __restrict__ skipb, float* __restrict__ s,
    float* __restrict__ d, unsigned int* __restrict__ smax_enc, int M, int K) {
  __shared__ unsigned short As[4][128 * 32];  // 32KB
  __shared__ unsigned short Bs[4][128 * 32];  // 32KB

  const int t = threadIdx.x;
  const int rowBase = blockIdx.y * 128;
  const int colBase = blockIdx.x * 128;  // 0..511
  const int w = t >> 6, lane = t & 63;
  const int wr = (w >> 1) * 64, wc = (w & 1) * 64;
  const int lrow = lane & 15, lq = lane >> 4;

  // Per-thread staging sources: chunks c0=t and c1=t+256 (16B each).
  const int r0 = t >> 2, seg = t & 3;
  int gr0 = rowBase + r0;       if (gr0 >= M) gr0 = M - 1;
  int gr1 = rowBase + 64 + r0;  if (gr1 >= M) gr1 = M - 1;
  const unsigned short* gA0 = xb + (size_t)gr0 * K + seg * 8;
  const unsigned short* gA1 = xb + (size_t)gr1 * K + seg * 8;
  const unsigned short* gB0 = Bt + (size_t)(colBase + r0) * K + seg * 8;
  const unsigned short* gB1 = Bt + (size_t)(colBase + 64 + r0) * K + seg * 8;

  // 32-bit LDS byte offsets for asm ds_read.
  const unsigned int asBase =
      (unsigned int)(size_t)(__attribute__((address_space(3))) unsigned short*)&As[0][0];
  const unsigned int bsBase =
      (unsigned int)(size_t)(__attribute__((address_space(3))) unsigned short*)&Bs[0][0];
  // fragment byte offset inside one buffer: row*64 + lq*16
  const unsigned int aFrag = (unsigned int)((wr + lrow) * 64 + lq * 16);
  const unsigned int bFrag = (unsigned int)((wc + lrow) * 64 + lq * 16);

  f32x4 acc[4][4];
#pragma unroll
  for (int i = 0; i < 4; i++)
#pragma unroll
    for (int j = 0; j < 4; j++) acc[i][j] = (f32x4){0.f, 0.f, 0.f, 0.f};

  const int nt = K >> 5;  // 4 or 8

  auto issue = [&](int stp) {
    const int buf = stp & 3;
    const int ko = stp * 32;
    gload_lds16(gA0 + ko, &As[buf][t * 8]);
    gload_lds16(gA1 + ko, &As[buf][(t + 256) * 8]);
    gload_lds16(gB0 + ko, &Bs[buf][t * 8]);
    gload_lds16(gB1 + ko, &Bs[buf][(t + 256) * 8]);
  };

  // prologue: 3 steps in flight (12 loads/wave)
  issue(0); issue(1); issue(2);

  for (int st = 0; st < nt; ++st) {
    // wait for step st's 4 loads; keep later steps' loads in flight
    if (st < nt - 2) {
      asm volatile("s_waitcnt vmcnt(8)" ::: "memory");
    } else if (st == nt - 2) {
      asm volatile("s_waitcnt vmcnt(4)" ::: "memory");
    } else {
      asm volatile("s_waitcnt vmcnt(0)" ::: "memory");
    }
    __builtin_amdgcn_s_barrier();
    __builtin_amdgcn_sched_barrier(0);
    if (st + 3 < nt) issue(st + 3);

    const unsigned int aB = asBase + (unsigned int)((st & 3) * 8192) + aFrag;
    const unsigned int bB = bsBase + (unsigned int)((st & 3) * 8192) + bFrag;
    bf16x8 af[4], bfr[4];
#pragma unroll
    for (int i = 0; i < 4; i++) {
      af[i]  = lds_read_b128(aB + (unsigned int)(i * 1024));
      bfr[i] = lds_read_b128(bB + (unsigned int)(i * 1024));
    }
    asm volatile("s_waitcnt lgkmcnt(0)" ::: "memory");
    __builtin_amdgcn_sched_barrier(0);
#pragma unroll
    for (int i = 0; i < 4; i++)
#pragma unroll
      for (int j = 0; j < 4; j++)
        acc[i][j] = __builtin_amdgcn_mfma_f32_16x16x32_bf16(af[i], bfr[j], acc[i][j], 0, 0, 0);
  }

  // Epilogue: C/D layout col=lane&15, row=(lane>>4)*4+reg
  if (colBase < 256) {
#pragma unroll
    for (int i = 0; i < 4; i++) {
#pragma unroll
      for (int j = 0; j < 4; j++) {
        int gcol = colBase + wc + j * 16 + lrow;
#pragma unroll
        for (int r = 0; r < 4; r++) {
          int grow = rowBase + wr + i * 16 + lq * 4 + r;
          if (grow < M) h[(size_t)grow * 256 + gcol] = f2bf(acc[i][j][r]);
        }
      }
    }
    // --- fused s/d + global per-head max ---
    int head = (colBase + wc) >> 6;  // 0..3, one head per wave
    float as_w[4], ad_w[4];
#pragma unroll
    for (int j = 0; j < 4; j++) {
      as_w[j] = a_src[head * 64 + j * 16 + lrow];
      ad_w[j] = a_dst[head * 64 + j * 16 + lrow];
    }
    float mymax = -1e30f;
#pragma unroll
    for (int i = 0; i < 4; i++) {
#pragma unroll
      for (int r = 0; r < 4; r++) {
        float ps = acc[i][0][r] * as_w[0] + acc[i][1][r] * as_w[1] +
                   acc[i][2][r] * as_w[2] + acc[i][3][r] * as_w[3];
        float pd = acc[i][0][r] * ad_w[0] + acc[i][1][r] * ad_w[1] +
                   acc[i][2][r] * ad_w[2] + acc[i][3][r] * ad_w[3];
#pragma unroll
        for (int off = 1; off < 16; off <<= 1) {  // reduce across lrow (same lq)
          ps += __shfl_xor(ps, off, 64);
          pd += __shfl_xor(pd, off, 64);
        }
        int grow = rowBase + wr + i * 16 + lq * 4 + r;
        if (grow < M) {
          if (lrow == 0) { s[grow * 4 + head] = ps; d[grow * 4 + head] = pd; }
          mymax = fmaxf(mymax, ps);
        }
      }
    }
    mymax = fmaxf(mymax, __shfl_xor(mymax, 16, 64));
    mymax = fmaxf(mymax, __shfl_xor(mymax, 32, 64));
    if (lane == 0) {
      unsigned int mb = __builtin_bit_cast(unsigned int, mymax);
      unsigned int key = (mb & 0x80000000u) ? ~mb : (mb | 0x80000000u);
      atomicMax(&smax_enc[head], key);
    }
  } else {
#pragma unroll
    for (int i = 0; i < 4; i++) {
#pragma unroll
      for (int j = 0; j < 4; j++) {
        int c = colBase - 256 + wc + j * 16 + lrow;
        float sbv = Sb[c];
#pragma unroll
        for (int r = 0; r < 4; r++) {
          int grow = rowBase + wr + i * 16 + lq * 4 + r;
          if (grow < M) skipb[(size_t)grow * 256 + c] = f2bf(acc[i][j][r] + sbv);
        }
      }
    }
  }
}

// ---------------------------------------------------------------------------
// CSR build (padded to multiple-of-8 segments). Segment ORDER is irrelevant,
// so the exclusive scan is replaced by wave-aggregated atomicAdd on a cursor.
// ---------------------------------------------------------------------------
__global__ void hist_kernel(const int* __restrict__ ei, int* __restrict__ counts, int E) {
  int e = blockIdx.x * 256 + threadIdx.x;
  if (e < E) atomicAdd(&counts[ei[E + e]], 1);
}

__global__ __launch_bounds__(256) void offsets_kernel(
    const int* __restrict__ counts, int* __restrict__ offsets,
    int* __restrict__ cursor, int* __restrict__ total, int Nn) {
  int n = blockIdx.x * 256 + threadIdx.x;
  int lane = threadIdx.x & 63;
  int pc = (n < Nn) ? ((counts[n] + 7) & ~7) : 0;
  int incl = pc;
#pragma unroll
  for (int off = 1; off < 64; off <<= 1) {
    int tv = __shfl_up(incl, off, 64);
    if (lane >= off) incl += tv;
  }
  int wavesum = __shfl(incl, 63, 64);
  int base = 0;
  if (lane == 63) base = atomicAdd(total, wavesum);
  base = __shfl(base, 63, 64);
  if (n < Nn) {
    int pos = base + incl - pc;
    offsets[n] = pos;
    cursor[n] = pos;
  }
}

__global__ void scatter_kernel(const int* __restrict__ ei, int* __restrict__ cursor,
                               int* __restrict__ csr, int E) {
  int e = blockIdx.x * 256 + threadIdx.x;
  if (e < E) {
    int dn = ei[E + e];
    int pos = atomicAdd(&cursor[dn], 1);
    csr[pos] = ei[e];
  }
}

__global__ void pad_kernel(const int* __restrict__ counts, const int* __restrict__ offsets,
                           int* __restrict__ csr, int Nn) {
  int n = blockIdx.x * 256 + threadIdx.x;
  if (n >= Nn) return;
  int c = counts[n];
  int e0 = offsets[n] + c;
  int e1 = offsets[n] + ((c + 7) & ~7);
  for (int i = e0; i < e1; i++) csr[i] = 0;
}

// ---------------------------------------------------------------------------
// Aggregation (fused edge softmax): one wave per node; 32 lanes per edge-row
// (8 cols/lane, b128 gathers); halves take interleaved 4-edge groups;
// combine via shfl_xor(32). exp(leaky(s+d)-m) computed inline.
// ---------------------------------------------------------------------------
__global__ __launch_bounds__(256) void agg_kernel(
    const unsigned short* __restrict__ hb, const float* __restrict__ s,
    const float* __restrict__ d, const unsigned int* __restrict__ smax_enc,
    const int* __restrict__ offsets, const int* __restrict__ counts,
    const int* __restrict__ csr,
    const float* __restrict__ b, const unsigned short* __restrict__ skipb,
    float* __restrict__ xout_f, unsigned short* __restrict__ xout_b,
    int Nn, int write_f) {
  int n = blockIdx.x * 4 + (threadIdx.x >> 6);
  if (n >= Nn) return;
  int lane = threadIdx.x & 63;
  int sub = lane >> 5;
  int li = lane & 31;
  int head = li >> 3;
  int col = li * 8;

  int beg = offsets[n];
  int cnt = counts[n];
  int rend = beg + cnt;
  int pend = beg + ((cnt + 7) & ~7);

  float dv = d[n * 4 + head];
  float m = leaky02(decode_max(smax_enc[head]) + dv);

  float a[8] = {0.f, 0.f, 0.f, 0.f, 0.f, 0.f, 0.f, 0.f};
  float dsum = 0.f;

  for (int i = beg + sub * 4; i < pend; i += 8) {
    int4 sn = *reinterpret_cast<const int4*>(csr + i);
    float s0 = s[sn.x * 4 + head];
    float s1 = s[sn.y * 4 + head];
    float s2 = s[sn.z * 4 + head];
    float s3 = s[sn.w * 4 + head];
    float ev0 = (i + 0 < rend) ? __expf(leaky02(s0 + dv) - m) : 0.f;
    float ev1 = (i + 1 < rend) ? __expf(leaky02(s1 + dv) - m) : 0.f;
    float ev2 = (i + 2 < rend) ? __expf(leaky02(s2 + dv) - m) : 0.f;
    float ev3 = (i + 3 < rend) ? __expf(leaky02(s3 + dv) - m) : 0.f;
    bf16x8 u0 = *reinterpret_cast<const bf16x8*>(hb + (size_t)sn.x * HC + col);
    bf16x8 u1 = *reinterpret_cast<const bf16x8*>(hb + (size_t)sn.y * HC + col);
    bf16x8 u2 = *reinterpret_cast<const bf16x8*>(hb + (size_t)sn.z * HC + col);
    bf16x8 u3 = *reinterpret_cast<const bf16x8*>(hb + (size_t)sn.w * HC + col);
#pragma unroll
    for (int k = 0; k < 8; k++) {
      a[k] += ev0 * bf2f((unsigned short)u0[k]) + ev1 * bf2f((unsigned short)u1[k]) +
              ev2 * bf2f((unsigned short)u2[k]) + ev3 * bf2f((unsigned short)u3[k]);
    }
    dsum += ev0 + ev1 + ev2 + ev3;
  }

#pragma unroll
  for (int k = 0; k < 8; k++) a[k] += __shfl_xor(a[k], 32, 64);
  dsum += __shfl_xor(dsum, 32, 64);

  // self loop
  float sv = s[n * 4 + head];
  float es = __expf(leaky02(sv + dv) - m);
  bf16x8 hs = *reinterpret_cast<const bf16x8*>(hb + (size_t)n * HC + col);
#pragma unroll
  for (int k = 0; k < 8; k++) a[k] += es * bf2f((unsigned short)hs[k]);
  dsum += es;

  if (sub == 0) {
    float inv = 1.f / (dsum + 1e-16f);
    bf16x8 sk = *reinterpret_cast<const bf16x8*>(skipb + (size_t)n * HC + col);
    float4 b0 = *reinterpret_cast<const float4*>(b + col);
    float4 b1 = *reinterpret_cast<const float4*>(b + col + 4);
    float bv[8] = {b0.x, b0.y, b0.z, b0.w, b1.x, b1.y, b1.z, b1.w};
    float res[8];
#pragma unroll
    for (int k = 0; k < 8; k++) {
      float v = a[k] * inv + bv[k] + bf2f((unsigned short)sk[k]);
      res[k] = v > 0.f ? v : expm1f(v);
    }
    if (write_f) {
      float4 r0 = make_float4(res[0], res[1], res[2], res[3]);
      float4 r1 = make_float4(res[4], res[5], res[6], res[7]);
      *reinterpret_cast<float4*>(xout_f + (size_t)n * HC + col) = r0;
      *reinterpret_cast<float4*>(xout_f + (size_t)n * HC + col + 4) = r1;
    } else {
      bf16x8 o;
#pragma unroll
      for (int k = 0; k < 8; k++) o[k] = (short)f2bf(res[k]);
      *reinterpret_cast<bf16x8*>(xout_b + (size_t)n * HC + col) = o;
    }
  }
}

// ---------------------------------------------------------------------------
extern "C" void kernel_launch(void* const* d_in, const int* in_sizes, int n_in,
                              void* d_out, int out_size, void* d_ws, size_t ws_size,
                              hipStream_t stream) {
  const float* x = (const float*)d_in[0];
  const int* ei = (const int*)d_in[1];
  const int Nn = in_sizes[0] / 128;  // 50000
  const int E = in_sizes[1] / 2;     // 800000
  const int EPS = E + 7 * Nn;        // max padded CSR size (pad-8)

  const float* W[3]; const float* asrc[3]; const float* adst[3];
  const float* bb[3]; const float* SW[3]; const float* Sb[3];
  for (int l = 0; l < 3; l++) {
    W[l]    = (const float*)d_in[2 + 6 * l + 0];
    asrc[l] = (const float*)d_in[2 + 6 * l + 1];
    adst[l] = (const float*)d_in[2 + 6 * l + 2];
    bb[l]   = (const float*)d_in[2 + 6 * l + 3];
    SW[l]   = (const float*)d_in[2 + 6 * l + 4];
    Sb[l]   = (const float*)d_in[2 + 6 * l + 5];
  }

  // Workspace layout (16B aligned chunks). counts, total, smax_enc adjacent so
  // a single memset clears all three (smax uses 4 slots per layer, 12 total).
  char* p = (char*)d_ws;
  unsigned short* hb    = (unsigned short*)p; p += (size_t)Nn * HC * 2;
  unsigned short* xb    = (unsigned short*)p; p += (size_t)Nn * HC * 2;
  unsigned short* x1b   = (unsigned short*)p; p += (size_t)Nn * 128 * 2;
  unsigned short* Bt0   = (unsigned short*)p; p += (size_t)512 * 128 * 2;
  unsigned short* Bt1   = (unsigned short*)p; p += (size_t)512 * 256 * 2;
  unsigned short* Bt2   = (unsigned short*)p; p += (size_t)512 * 256 * 2;
  unsigned short* skipb = (unsigned short*)p; p += (size_t)Nn * HC * 2;
  float* sbuf  = (float*)p; p += (size_t)Nn * HEADS * 4;
  float* dbuf  = (float*)p; p += (size_t)Nn * HEADS * 4;
  int* counts  = (int*)p; p += (size_t)Nn * 4;
  int* total   = (int*)p; p += 16;
  unsigned int* smax_enc = (unsigned int*)p; p += 64;
  int* offsets = (int*)p; p += ((size_t)Nn * 4 + 15) & ~(size_t)15;
  int* cursor  = (int*)p; p += ((size_t)Nn * 4 + 15) & ~(size_t)15;
  int* csr     = (int*)p; p += (size_t)EPS * 4;

  // --- Weight transposes for all 3 layers up front (no per-layer bubbles) ---
  transpose_w<<<dim3(2, 8), 256, 0, stream>>>(W[0], SW[0], Bt0, 128);
  transpose_w<<<dim3(4, 8), 256, 0, stream>>>(W[1], SW[1], Bt1, 256);
  transpose_w<<<dim3(4, 8), 256, 0, stream>>>(W[2], SW[2], Bt2, 256);

  // --- CSR build (once; dst is layer-invariant). One memset covers
  // counts+total+smax. Segment order is atomic-assigned (irrelevant to result).
  hipMemsetAsync(counts, 0, (size_t)Nn * 4 + 16 + 64, stream);
  hist_kernel<<<(E + 255) / 256, 256, 0, stream>>>(ei, counts, E);
  offsets_kernel<<<(Nn + 255) / 256, 256, 0, stream>>>(counts, offsets, cursor, total, Nn);
  scatter_kernel<<<(E + 255) / 256, 256, 0, stream>>>(ei, cursor, csr, E);
  pad_kernel<<<(Nn + 255) / 256, 256, 0, stream>>>(counts, offsets, csr, Nn);

  // --- Input conversion ---
  int t4 = Nn * 128 / 4;
  convert_x<<<(t4 + 255) / 256, 256, 0, stream>>>(x, x1b, t4);

  // --- Layers ---
  const unsigned short* BtL[3] = {Bt0, Bt1, Bt2};
  dim3 ggrid(4, (Nn + 127) / 128);
  int nblk4 = (Nn + 3) / 4;
  for (int l = 0; l < 3; l++) {
    int K = (l == 0) ? 128 : 256;
    const unsigned short* xin = (l == 0) ? x1b : xb;
    unsigned int* sme = smax_enc + 4 * l;
    gemm_mfma<<<ggrid, 256, 0, stream>>>(xin, BtL[l], Sb[l], asrc[l], adst[l],
                                         hb, skipb, sbuf, dbuf, sme, Nn, K);
    agg_kernel<<<nblk4, 256, 0, stream>>>(hb, sbuf, dbuf, sme, offsets, counts, csr,
                                          bb[l], skipb, (float*)d_out, xb,
                                          Nn, (l == 2) ? 1 : 0);
  }
}